// Round 18
// baseline (194.561 us; speedup 1.0000x reference)
//
#include <hip/hip_runtime.h>
#include <stdint.h>

#define N_NODES 10000
#define N_EDGES 160000
#define HID 512
#define EDIM 128
#define K1 640
#define BM 64
#define LN_EPS 1e-5f
#define PRE_BLOCKS 157    // ceil(10000/64)
#define WC_BLOCKS 9
#define FILL_BLOCKS 313   // ceil(160000/512)
#define ZB_BLOCKS 2500    // hsum zero: 2500*512 threads * 16B
#define TR_BLOCKS 3328    // weight transposes
#define CNT_BLOCKS 625    // count: ceil(160000/256)
#define EDGE_BLOCKS 2500  // N_EDGES / BM
#define NS_BLOCKS 157     // node_self tiles

typedef __attribute__((ext_vector_type(4))) float f32x4;
typedef __attribute__((ext_vector_type(8))) short bf16x8;
typedef __attribute__((ext_vector_type(4))) short bf16x4;

__device__ __forceinline__ short f2bf(float f) {
  unsigned u = __float_as_uint(f);
  u += 0x7fff + ((u >> 16) & 1);
  return (short)(u >> 16);
}
__device__ __forceinline__ float bf2f(short s) {
  return __uint_as_float(((unsigned)(unsigned short)s) << 16);
}
// tanh-form GELU in exp2 domain
__device__ __forceinline__ float gelu_f(float x) {
  float t = x * x;
  float zn = x * fmaf(t, -0.10293960f, -2.30220795f);
  return x * __builtin_amdgcn_rcpf(1.0f + __builtin_amdgcn_exp2f(zn));
}

#define GLDS(g, l) __builtin_amdgcn_global_load_lds( \
    (const __attribute__((address_space(1))) void*)(g), \
    (__attribute__((address_space(3))) void*)(l), 16, 0, 0)

// ---------------------------------------------------------------------------
// init: weight transposes f32->bf16 (blocks 0..3327) | in-degree count
// (3328..; icnt pre-zeroed by hipMemsetAsync).
// ---------------------------------------------------------------------------
__global__ __launch_bounds__(256) void init_kernel(
    int* __restrict__ icnt, const int* __restrict__ tgts,
    const float* __restrict__ w1, const float* __restrict__ sw,
    const float* __restrict__ aw,
    short* __restrict__ w1T, short* __restrict__ swT, short* __restrict__ awT)
{
  const int bx = blockIdx.x, tid = threadIdx.x;
  if (bx < TR_BLOCKS) {
    int id = bx * 256 + tid;
    const int NW1 = HID * K1, NSQ = HID * HID;
    if (id < NW1) {
      int n = id / K1, k = id - n * K1;
      w1T[id] = f2bf(w1[(size_t)k * HID + n]);
    } else if (id < NW1 + NSQ) {
      int i = id - NW1; int n = i >> 9, k = i & (HID - 1);
      swT[i] = f2bf(sw[(size_t)k * HID + n]);
    } else if (id < NW1 + 2 * NSQ) {
      int i = id - NW1 - NSQ; int n = i >> 9, k = i & (HID - 1);
      awT[i] = f2bf(aw[(size_t)k * HID + n]);
    }
  } else {
    int i = (bx - TR_BLOCKS) * 256 + tid;
    if (i < N_EDGES) atomicAdd(&icnt[tgts[i]], 1);
  }
}

// ---------------------------------------------------------------------------
// scan: icnt -> cursor (exclusive prefix), standalone 1-block kernel
// ---------------------------------------------------------------------------
__global__ __launch_bounds__(512) void scan_kernel(const int* __restrict__ icnt,
                                                   int* __restrict__ cursor)
{
  __shared__ int sums[512];
  const int tid = threadIdx.x;
  const int CH = 20;  // 512*20 = 10240 >= N_NODES
  int loc[CH];
  int s = 0;
#pragma unroll
  for (int i = 0; i < CH; ++i) {
    int idx = tid * CH + i;
    int v = (idx < N_NODES) ? icnt[idx] : 0;
    loc[i] = s; s += v;
  }
  sums[tid] = s;
  __syncthreads();
  for (int d = 1; d < 512; d <<= 1) {
    int v = (tid >= d) ? sums[tid - d] : 0;
    __syncthreads();
    sums[tid] += v;
    __syncthreads();
  }
  int base = (tid == 0) ? 0 : sums[tid - 1];
#pragma unroll
  for (int i = 0; i < CH; ++i) {
    int idx = tid * CH + i;
    if (idx < N_NODES) cursor[idx] = base + loc[i];
  }
}

// ---------------------------------------------------------------------------
// Fused dispatch:
//  blocks [0,157): Pb = bf16(ns @ w1_top + b1), PERMUTED col layout
//  blocks [157,166): [WT | bvec] = ([w2; b2] @ agg_w)
//  blocks [166,479): fill — scatter sorted / sorted_src / sorted_tgt
//  blocks [479,2979): hsum zeroing
// ---------------------------------------------------------------------------
__global__ __launch_bounds__(512, 2) void gemm_prep_kernel(
    const float* __restrict__ node_state, const float* __restrict__ b1,
    const short* __restrict__ w1T,
    short* __restrict__ Pb,
    const float* __restrict__ w2, const float* __restrict__ b2,
    const short* __restrict__ awT,
    short* __restrict__ WT, float* __restrict__ bvec,
    const int* __restrict__ srcs, const int* __restrict__ tgts,
    int* __restrict__ cursor,
    int* __restrict__ sorted, int* __restrict__ sorted_src,
    int* __restrict__ sorted_tgt,
    float* __restrict__ hsum)
{
  const int tid = threadIdx.x;

  if (blockIdx.x >= PRE_BLOCKS + WC_BLOCKS + FILL_BLOCKS) {
    int idx = (blockIdx.x - PRE_BLOCKS - WC_BLOCKS - FILL_BLOCKS) * 512 + tid;
    if (idx < N_NODES * HID / 4) {
      f32x4 z = {0.f, 0.f, 0.f, 0.f};
      *(f32x4*)(hsum + (size_t)idx * 4) = z;
    }
    return;
  }
  if (blockIdx.x >= PRE_BLOCKS + WC_BLOCKS) {
    int i = (blockIdx.x - PRE_BLOCKS - WC_BLOCKS) * 512 + tid;
    if (i < N_EDGES) {
      int tg = tgts[i];
      int p = atomicAdd(&cursor[tg], 1);
      sorted[p] = i;
      sorted_src[p] = srcs[i];
      sorted_tgt[p] = tg;
    }
    return;
  }

  __shared__ short As[2][BM * 32];
  __shared__ short Bs[2][HID * 32];

  const int lane = tid & 63, wv = tid >> 6;
  const int r16 = lane & 15, q4 = lane >> 4;
  const int arow = tid >> 2, auk = tid & 3;

  f32x4 acc[4][4] = {};
  f32x4 a0, a1;

  auto writeA = [&](int buf) {
    if (tid < 256) {
      bf16x8 v;
      v[0] = f2bf(a0[0]); v[1] = f2bf(a0[1]); v[2] = f2bf(a0[2]); v[3] = f2bf(a0[3]);
      v[4] = f2bf(a1[0]); v[5] = f2bf(a1[1]); v[6] = f2bf(a1[2]); v[7] = f2bf(a1[3]);
      int pos = arow * 4 + ((auk + (arow >> 1)) & 3);
      *(bf16x8*)(&As[buf][pos * 8]) = v;
    }
  };
  auto mma = [&](int buf) {
    bf16x8 af[4];
#pragma unroll
    for (int mi = 0; mi < 4; ++mi) {
      int row = mi * 16 + r16;
      int pos = row * 4 + ((q4 + (row >> 1)) & 3);
      af[mi] = *(const bf16x8*)(&As[buf][pos * 8]);
    }
#pragma unroll
    for (int ni = 0; ni < 4; ++ni) {
      int n = wv * 64 + ni * 16 + r16;
      int pos = n * 4 + ((q4 + (n >> 1)) & 3);
      bf16x8 bfr = *(const bf16x8*)(&Bs[buf][pos * 8]);
#pragma unroll
      for (int mi = 0; mi < 4; ++mi)
        acc[mi][ni] = __builtin_amdgcn_mfma_f32_16x16x32_bf16(af[mi], bfr, acc[mi][ni], 0, 0, 0);
    }
  };

  if (blockIdx.x < PRE_BLOCKS) {
    // ---------------- pre_msg path ----------------
    const int n0 = blockIdx.x * BM;
    float b1v[4];
#pragma unroll
    for (int ni = 0; ni < 4; ++ni) b1v[ni] = b1[wv * 64 + ni * 16 + r16];

    const int ga = min(n0 + arow, N_NODES - 1);
    auto loadA = [&](int k0) {
      if (tid < 256) {
        const float* p = node_state + (size_t)ga * HID + k0 + auk * 8;
        a0 = *(const f32x4*)p; a1 = *(const f32x4*)(p + 4);
      }
    };
    auto stageB = [&](int k0, int buf) {
#pragma unroll
      for (int i = 0; i < 4; ++i) {
        int q = i * 512 + tid;
        int n = q >> 2;
        int uk = ((q & 3) - (n >> 1)) & 3;
        GLDS(w1T + (size_t)n * K1 + k0 + uk * 8, &Bs[buf][(i * 512 + wv * 64) * 8]);
      }
    };

    stageB(0, 0); loadA(0); writeA(0);
    __syncthreads();
#pragma unroll 1
    for (int s = 0; s < 16; ++s) {
      int cur = s & 1, nxt = cur ^ 1;
      if (s < 15) { stageB((s + 1) * 32, nxt); loadA((s + 1) * 32); }
      mma(cur);
      if (s < 15) writeA(nxt);
      __syncthreads();
    }

    // permuted, packed 8B stores
#pragma unroll
    for (int mi = 0; mi < 4; ++mi)
#pragma unroll
      for (int j = 0; j < 4; ++j) {
        int g = n0 + mi * 16 + q4 * 4 + j;
        if (g < N_NODES) {
          bf16x4 pk;
#pragma unroll
          for (int ni = 0; ni < 4; ++ni) pk[ni] = f2bf(acc[mi][ni][j] + b1v[ni]);
          *(bf16x4*)(Pb + (size_t)g * HID + wv * 64 + r16 * 4) = pk;
        }
      }
  } else {
    // ---------------- wcombine path ----------------
    const int m0 = (blockIdx.x - PRE_BLOCKS) * BM;
    const int gm = min(m0 + arow, HID);   // HID => b2 row
    auto loadA = [&](int k0) {
      if (tid < 256) {
        const float* base = (gm < HID) ? w2 + (size_t)gm * HID : b2;
        const float* p = base + k0 + auk * 8;
        a0 = *(const f32x4*)p; a1 = *(const f32x4*)(p + 4);
      }
    };
    auto stageB = [&](int k0, int buf) {
#pragma unroll
      for (int i = 0; i < 4; ++i) {
        int q = i * 512 + tid;
        int n = q >> 2;
        int uk = ((q & 3) - (n >> 1)) & 3;
        GLDS(awT + (size_t)n * HID + k0 + uk * 8, &Bs[buf][(i * 512 + wv * 64) * 8]);
      }
    };

    stageB(0, 0); loadA(0); writeA(0);
    __syncthreads();
#pragma unroll 1
    for (int s = 0; s < 16; ++s) {
      int cur = s & 1, nxt = cur ^ 1;
      if (s < 15) { stageB((s + 1) * 32, nxt); loadA((s + 1) * 32); }
      mma(cur);
      if (s < 15) writeA(nxt);
      __syncthreads();
    }

#pragma unroll
    for (int mi = 0; mi < 4; ++mi)
#pragma unroll
      for (int j = 0; j < 4; ++j) {
        int m = m0 + mi * 16 + q4 * 4 + j;
        if (m < HID) {
#pragma unroll
          for (int ni = 0; ni < 4; ++ni)
            WT[(size_t)(wv * 64 + ni * 16 + r16) * HID + m] = f2bf(acc[mi][ni][j]);
        } else if (m == HID) {
#pragma unroll
          for (int ni = 0; ni < 4; ++ni)
            bvec[wv * 64 + ni * 16 + r16] = acc[mi][ni][j];
        }
      }
  }
}

// ---------------------------------------------------------------------------
// Edge dispatch (node_self FIRST; edge blocks backfill):
//  blocks [0,157): node_self — u1 = ns @ swT, PERMUTED f32x4 output
//  blocks [157,2657): edge tiles (coalesced prologue via sorted_src/tgt)
// ---------------------------------------------------------------------------
__global__ __launch_bounds__(512, 2) void edge_msg_kernel(
    const float* __restrict__ edge_emb, const short* __restrict__ Pb,
    const int* __restrict__ sorted, const int* __restrict__ sorted_src,
    const int* __restrict__ sorted_tgt,
    const short* __restrict__ w1T,
    float* __restrict__ hsum,
    const float* __restrict__ node_state, const short* __restrict__ swT,
    float* __restrict__ u1)
{
  __shared__ short As[2][BM * 32];
  __shared__ short Bs[2][HID * 32];
  __shared__ int src_l[BM], eid_l[BM];

  const int tid = threadIdx.x, lane = tid & 63, wv = tid >> 6;
  const int r16 = lane & 15, q4 = lane >> 4;
  const int arow = tid >> 2, auk = tid & 3;
  f32x4 a0, a1;

  auto writeA = [&](int buf) {
    if (tid < 256) {
      bf16x8 v;
      v[0] = f2bf(a0[0]); v[1] = f2bf(a0[1]); v[2] = f2bf(a0[2]); v[3] = f2bf(a0[3]);
      v[4] = f2bf(a1[0]); v[5] = f2bf(a1[1]); v[6] = f2bf(a1[2]); v[7] = f2bf(a1[3]);
      int pos = arow * 4 + ((auk + (arow >> 1)) & 3);
      *(bf16x8*)(&As[buf][pos * 8]) = v;
    }
  };

  if (blockIdx.x < NS_BLOCKS) {
    // ---------------- node_self path: u1 = ns @ swT ----------------
    const int n0 = blockIdx.x * BM;
    const int ga = min(n0 + arow, N_NODES - 1);

    f32x4 acc[4][4] = {};
    auto loadA = [&](int k0) {
      if (tid < 256) {
        const float* p = node_state + (size_t)ga * HID + k0 + auk * 8;
        a0 = *(const f32x4*)p; a1 = *(const f32x4*)(p + 4);
      }
    };
    auto stageB = [&](int k0, int buf) {
#pragma unroll
      for (int i = 0; i < 4; ++i) {
        int q = i * 512 + tid;
        int n = q >> 2;
        int uk = ((q & 3) - (n >> 1)) & 3;
        GLDS(swT + (size_t)n * HID + k0 + uk * 8, &Bs[buf][(i * 512 + wv * 64) * 8]);
      }
    };
    auto mma = [&](int buf) {
      bf16x8 af[4];
#pragma unroll
      for (int mi = 0; mi < 4; ++mi) {
        int row = mi * 16 + r16;
        int pos = row * 4 + ((q4 + (row >> 1)) & 3);
        af[mi] = *(const bf16x8*)(&As[buf][pos * 8]);
      }
#pragma unroll
      for (int ni = 0; ni < 4; ++ni) {
        int n = wv * 64 + ni * 16 + r16;
        int pos = n * 4 + ((q4 + (n >> 1)) & 3);
        bf16x8 bfr = *(const bf16x8*)(&Bs[buf][pos * 8]);
#pragma unroll
        for (int mi = 0; mi < 4; ++mi)
          acc[mi][ni] = __builtin_amdgcn_mfma_f32_16x16x32_bf16(af[mi], bfr, acc[mi][ni], 0, 0, 0);
      }
    };

    stageB(0, 0); loadA(0); writeA(0);
    __syncthreads();
#pragma unroll 1
    for (int s = 0; s < 16; ++s) {
      int cur = s & 1, nxt = cur ^ 1;
      if (s < 15) { stageB((s + 1) * 32, nxt); loadA((s + 1) * 32); }
      mma(cur);
      if (s < 15) writeA(nxt);
      __syncthreads();
    }

    // permuted f32x4 stores (mirror of Pb layout)
#pragma unroll
    for (int mi = 0; mi < 4; ++mi)
#pragma unroll
      for (int j = 0; j < 4; ++j) {
        int g = n0 + mi * 16 + q4 * 4 + j;
        if (g < N_NODES) {
          f32x4 uv;
#pragma unroll
          for (int ni = 0; ni < 4; ++ni) uv[ni] = acc[mi][ni][j];
          *(f32x4*)(u1 + (size_t)g * HID + wv * 64 + r16 * 4) = uv;
        }
      }
    return;
  }

  // ---------------- edge path ----------------
  const int e0 = (blockIdx.x - NS_BLOCKS) * BM;

  if (tid < BM) {
    eid_l[tid] = sorted[e0 + tid];
    src_l[tid] = sorted_src[e0 + tid];
  }
  const int t_lane = sorted_tgt[e0 + lane];
  __syncthreads();

  // acc pre-init: permuted Pb gather — one 8B load per row
  f32x4 acc[4][4];
#pragma unroll
  for (int mi = 0; mi < 4; ++mi)
#pragma unroll
    for (int j = 0; j < 4; ++j) {
      int row = mi * 16 + q4 * 4 + j;
      bf16x4 v = *(const bf16x4*)(Pb + (size_t)src_l[row] * HID + wv * 64 + r16 * 4);
#pragma unroll
      for (int ni = 0; ni < 4; ++ni)
        acc[mi][ni][j] = bf2f(v[ni]);
    }

  auto loadA = [&](int k0) {
    if (tid < 256) {
      const float* p = edge_emb + (size_t)eid_l[arow] * EDIM + k0 + auk * 8;
      a0 = *(const f32x4*)p; a1 = *(const f32x4*)(p + 4);
    }
  };
  auto stageB = [&](int k0, int buf) {
#pragma unroll
    for (int i = 0; i < 4; ++i) {
      int q = i * 512 + tid;
      int n = q >> 2;
      int uk = ((q & 3) - (n >> 1)) & 3;
      GLDS(w1T + (size_t)n * K1 + 512 + k0 + uk * 8, &Bs[buf][(i * 512 + wv * 64) * 8]);
    }
  };
  auto mma = [&](int buf) {
    bf16x8 af[4];
#pragma unroll
    for (int mi = 0; mi < 4; ++mi) {
      int row = mi * 16 + r16;
      int pos = row * 4 + ((q4 + (row >> 1)) & 3);
      af[mi] = *(const bf16x8*)(&As[buf][pos * 8]);
    }
#pragma unroll
    for (int ni = 0; ni < 4; ++ni) {
      int n = wv * 64 + ni * 16 + r16;
      int pos = n * 4 + ((q4 + (n >> 1)) & 3);
      bf16x8 bfr = *(const bf16x8*)(&Bs[buf][pos * 8]);
#pragma unroll
      for (int mi = 0; mi < 4; ++mi)
        acc[mi][ni] = __builtin_amdgcn_mfma_f32_16x16x32_bf16(af[mi], bfr, acc[mi][ni], 0, 0, 0);
    }
  };

  stageB(0, 0); loadA(0); writeA(0);
  __syncthreads();
#pragma unroll 1
  for (int s = 0; s < 4; ++s) {
    int cur = s & 1, nxt = cur ^ 1;
    if (s < 3) { stageB((s + 1) * 32, nxt); loadA((s + 1) * 32); }
    mma(cur);
    if (s < 3) writeA(nxt);
    __syncthreads();
  }

  // epilogue
#pragma unroll
  for (int mi = 0; mi < 4; ++mi)
#pragma unroll
    for (int ni = 0; ni < 4; ++ni)
#pragma unroll
      for (int j = 0; j < 4; ++j)
        acc[mi][ni][j] = gelu_f(acc[mi][ni][j]);

  int t_prev = __shfl_up(t_lane, 1, 64);
  bool bnd = (lane == 0) || (t_lane != t_prev);
  unsigned long long bmask = __ballot(bnd);

  int s = 0;
  while (s < BM) {
    int t = __shfl(t_lane, s, 64);
    unsigned long long above = (s < 63) ? (bmask >> (s + 1)) : 0ull;
    int e = (above == 0ull) ? BM : (s + 1 + (int)__builtin_ctzll(above));
    bool boundary = (s == 0) || (e == BM);

    float sum[4] = {0.f, 0.f, 0.f, 0.f};
#pragma unroll
    for (int mi = 0; mi < 4; ++mi) {
      if (e > mi * 16 && s < mi * 16 + 16) {  // wave-uniform skip
#pragma unroll
        for (int j = 0; j < 4; ++j) {
          int row = mi * 16 + q4 * 4 + j;
          bool in = (row >= s) && (row < e);
#pragma unroll
          for (int ni = 0; ni < 4; ++ni)
            sum[ni] += in ? acc[mi][ni][j] : 0.0f;
        }
      }
    }
#pragma unroll
    for (int ni = 0; ni < 4; ++ni) {
      sum[ni] += __shfl_xor(sum[ni], 16, 64);
      sum[ni] += __shfl_xor(sum[ni], 32, 64);
    }
    if (q4 == 0) {
      float* dst = hsum + (size_t)t * HID + wv * 64 + r16;
      if (boundary) {
#pragma unroll
        for (int ni = 0; ni < 4; ++ni) atomicAdd(dst + ni * 16, sum[ni]);
      } else {
#pragma unroll
        for (int ni = 0; ni < 4; ++ni) dst[ni * 16] = sum[ni];
      }
    }
    s = e;
  }
}

// ---------------------------------------------------------------------------
// node_final: acc = (hsum*invc) @ WT (16 K-steps);
// u = acc + u1 + self_b+agg_b + flag*bvec; out = LN(ns + gelu(u))
// ---------------------------------------------------------------------------
__global__ __launch_bounds__(512, 2) void node_final_kernel(
    const float* __restrict__ node_state, const float* __restrict__ hsum,
    const float* __restrict__ u1,
    const int* __restrict__ icnt,
    const short* __restrict__ WT,
    const float* __restrict__ self_b, const float* __restrict__ agg_b,
    const float* __restrict__ bvec,
    const float* __restrict__ gamma, const float* __restrict__ beta,
    float* __restrict__ out)
{
  __shared__ short As[2][BM * 32];
  __shared__ short Bs[2][HID * 32];
  __shared__ float cfl[BM], invc_l[BM];
  __shared__ float wsum[8][BM], wsq[8][BM];
  __shared__ float stats[BM][2];

  const int tid = threadIdx.x, lane = tid & 63, wv = tid >> 6;
  const int r16 = lane & 15, q4 = lane >> 4;
  const int n0 = blockIdx.x * BM;

  if (tid < BM) {
    int g = n0 + tid;
    int c = (g < N_NODES) ? icnt[g] : 0;
    cfl[tid] = (c > 0) ? 1.0f : 0.0f;
    invc_l[tid] = 1.0f / (float)max(c, 1);
  }

  float bb[4], bv[4], gam[4], bet[4];
#pragma unroll
  for (int ni = 0; ni < 4; ++ni) {
    int c = wv * 64 + ni * 16 + r16;
    bb[ni] = self_b[c] + agg_b[c];
    bv[ni] = bvec[c];
    gam[ni] = gamma[c]; bet[ni] = beta[c];
  }
  __syncthreads();

  const int arow = tid >> 2, auk = tid & 3;
  const int ga = min(n0 + arow, N_NODES - 1);
  f32x4 a0, a1;

  auto loadA = [&](int k0) {
    if (tid < 256) {
      const float* p = hsum + (size_t)ga * HID + k0 + auk * 8;
      a0 = *(const f32x4*)p; a1 = *(const f32x4*)(p + 4);
      float s = invc_l[arow]; a0 *= s; a1 *= s;
    }
  };
  auto writeA = [&](int buf) {
    if (tid < 256) {
      bf16x8 v;
      v[0] = f2bf(a0[0]); v[1] = f2bf(a0[1]); v[2] = f2bf(a0[2]); v[3] = f2bf(a0[3]);
      v[4] = f2bf(a1[0]); v[5] = f2bf(a1[1]); v[6] = f2bf(a1[2]); v[7] = f2bf(a1[3]);
      int pos = arow * 4 + ((auk + (arow >> 1)) & 3);
      *(bf16x8*)(&As[buf][pos * 8]) = v;
    }
  };
  auto stageB = [&](int k0, int buf) {
#pragma unroll
    for (int i = 0; i < 4; ++i) {
      int q = i * 512 + tid;
      int n = q >> 2;
      int uk = ((q & 3) - (n >> 1)) & 3;
      GLDS(WT + (size_t)n * HID + k0 + uk * 8, &Bs[buf][(i * 512 + wv * 64) * 8]);
    }
  };

  f32x4 acc[4][4] = {};

  auto mma = [&](int buf) {
    bf16x8 af[4];
#pragma unroll
    for (int mi = 0; mi < 4; ++mi) {
      int row = mi * 16 + r16;
      int pos = row * 4 + ((q4 + (row >> 1)) & 3);
      af[mi] = *(const bf16x8*)(&As[buf][pos * 8]);
    }
#pragma unroll
    for (int ni = 0; ni < 4; ++ni) {
      int n = wv * 64 + ni * 16 + r16;
      int pos = n * 4 + ((q4 + (n >> 1)) & 3);
      bf16x8 bfr = *(const bf16x8*)(&Bs[buf][pos * 8]);
#pragma unroll
      for (int mi = 0; mi < 4; ++mi)
        acc[mi][ni] = __builtin_amdgcn_mfma_f32_16x16x32_bf16(af[mi], bfr, acc[mi][ni], 0, 0, 0);
    }
  };

  stageB(0, 0);
  loadA(0); writeA(0);
  __syncthreads();
#pragma unroll 1
  for (int s = 0; s < 16; ++s) {
    int cur = s & 1, nxt = cur ^ 1;
    if (s < 15) { stageB((s + 1) * 32, nxt); loadA((s + 1) * 32); }
    mma(cur);
    if (s < 15) writeA(nxt);
    __syncthreads();
  }

  // epilogue: + u1 (permuted f32x4) + biases, gelu, residual, LN
  float ps[4][4], ps2[4][4];
#pragma unroll
  for (int mi = 0; mi < 4; ++mi)
#pragma unroll
    for (int j = 0; j < 4; ++j) {
      int row = mi * 16 + q4 * 4 + j;
      int g = min(n0 + row, N_NODES - 1);
      float fl = cfl[row];
      f32x4 uv = *(const f32x4*)(u1 + (size_t)g * HID + wv * 64 + r16 * 4);
      float s1 = 0.f, s2 = 0.f;
#pragma unroll
      for (int ni = 0; ni < 4; ++ni) {
        float u = acc[mi][ni][j] + uv[ni] + bb[ni] + fl * bv[ni];
        float ns = node_state[(size_t)g * HID + wv * 64 + ni * 16 + r16];
        float x = ns + gelu_f(u);
        acc[mi][ni][j] = x;
        s1 += x; s2 += x * x;
      }
      ps[mi][j] = s1; ps2[mi][j] = s2;
    }
#pragma unroll
  for (int mi = 0; mi < 4; ++mi)
#pragma unroll
    for (int j = 0; j < 4; ++j) {
#pragma unroll
      for (int m = 1; m < 16; m <<= 1) {
        ps[mi][j] += __shfl_xor(ps[mi][j], m, 64);
        ps2[mi][j] += __shfl_xor(ps2[mi][j], m, 64);
      }
    }
  if (r16 == 0) {
#pragma unroll
    for (int mi = 0; mi < 4; ++mi)
#pragma unroll
      for (int j = 0; j < 4; ++j) {
        int row = mi * 16 + q4 * 4 + j;
        wsum[wv][row] = ps[mi][j]; wsq[wv][row] = ps2[mi][j];
      }
  }
  __syncthreads();
  if (tid < BM) {
    float s1 = 0.f, s2 = 0.f;
#pragma unroll
    for (int k = 0; k < 8; ++k) { s1 += wsum[k][tid]; s2 += wsq[k][tid]; }
    float mu = s1 * (1.0f / HID);
    float var = s2 * (1.0f / HID) - mu * mu;
    stats[tid][0] = mu; stats[tid][1] = rsqrtf(var + LN_EPS);
  }
  __syncthreads();
#pragma unroll
  for (int mi = 0; mi < 4; ++mi)
#pragma unroll
    for (int j = 0; j < 4; ++j) {
      int row = mi * 16 + q4 * 4 + j;
      int g = n0 + row;
      if (g < N_NODES) {
        float mu = stats[row][0], rs = stats[row][1];
#pragma unroll
        for (int ni = 0; ni < 4; ++ni)
          out[(size_t)g * HID + wv * 64 + ni * 16 + r16] =
              (acc[mi][ni][j] - mu) * rs * gam[ni] + bet[ni];
      }
    }
}

// ---------------------------------------------------------------------------
extern "C" void kernel_launch(void* const* d_in, const int* in_sizes, int n_in,
                              void* d_out, int out_size, void* d_ws, size_t ws_size,
                              hipStream_t stream)
{
  const float* node_state = (const float*)d_in[0];
  const int*   eidx       = (const int*)d_in[1];
  const float* edge_emb   = (const float*)d_in[2];
  const float* msg_w1     = (const float*)d_in[3];
  const float* msg_b1     = (const float*)d_in[4];
  const float* msg_w2     = (const float*)d_in[5];
  const float* msg_b2     = (const float*)d_in[6];
  const float* self_w     = (const float*)d_in[7];
  const float* self_b     = (const float*)d_in[8];
  const float* agg_w      = (const float*)d_in[9];
  const float* agg_b      = (const float*)d_in[10];
  const float* ln_gamma   = (const float*)d_in[11];
  const float* ln_beta    = (const float*)d_in[12];

  const int* srcs = eidx;
  const int* tgts = eidx + N_EDGES;
  float* out = (float*)d_out;
  char* ws = (char*)d_ws;

  float* hsum       = (float*)ws;                   // 20,480,000
  float* u1         = (float*)(ws + 20480000);      // 20,480,000
  short* Pb         = (short*)(ws + 40960000);      // 10,240,000
  int* icnt         = (int*)(ws + 51200000);        //     40,000
  int* cursor       = (int*)(ws + 51240192);        //     40,000
  int* sorted       = (int*)(ws + 51280384);        //    640,000
  int* sorted_src   = (int*)(ws + 51920384);        //    640,000
  int* sorted_tgt   = (int*)(ws + 52560384);        //    640,000
  short* w1T        = (short*)(ws + 53200384);      //    655,360
  short* swT        = (short*)(ws + 53855744);      //    524,288
  short* WT         = (short*)(ws + 54380032);      //    524,288
  short* awT        = (short*)(ws + 54904320);      //    524,288
  float* bvec       = (float*)(ws + 55428608);      //      2,048

  // 0) zero icnt (init's count blocks accumulate into it)
  hipMemsetAsync(icnt, 0, 40000, stream);

  // 1) init: weight transposes (3328) | in-degree count (625)
  init_kernel<<<TR_BLOCKS + CNT_BLOCKS, 256, 0, stream>>>(
      icnt, tgts, msg_w1, self_w, agg_w, w1T, swT, awT);

  // 2) scan (tiny, standalone — provides cursor for fill inside gemm_prep)
  scan_kernel<<<1, 512, 0, stream>>>(icnt, cursor);

  // 3) pre_msg (157) || wcombine (9) || fill (313) || hsum zero (2500)
  gemm_prep_kernel<<<PRE_BLOCKS + WC_BLOCKS + FILL_BLOCKS + ZB_BLOCKS, 512, 0, stream>>>(
      node_state, msg_b1, w1T, Pb, msg_w2, msg_b2, awT, WT, bvec,
      srcs, tgts, cursor, sorted, sorted_src, sorted_tgt, hsum);

  // 4) node_self u1 = ns @ swT (157, first) || edge tiles (2500)
  edge_msg_kernel<<<NS_BLOCKS + EDGE_BLOCKS, 512, 0, stream>>>(
      edge_emb, Pb, sorted, sorted_src, sorted_tgt, w1T, hsum,
      node_state, swT, u1);

  // 5) node_final: K=512 (hmean @ WT) + u1 + epilogue/LN
  node_final_kernel<<<(N_NODES + BM - 1) / BM, 512, 0, stream>>>(
      node_state, hsum, u1, icnt, WT, self_b, agg_b, bvec, ln_gamma, ln_beta, out);
}

// Round 19
// 190.242 us; speedup vs baseline: 1.0227x; 1.0227x over previous
//
#include <hip/hip_runtime.h>
#include <stdint.h>

#define N_NODES 10000
#define N_EDGES 160000
#define HID 512
#define EDIM 128
#define K1 640
#define BM 64
#define LN_EPS 1e-5f
#define PRE_BLOCKS 157    // ceil(10000/64)
#define ZB_BLOCKS 2500    // hsum zero: 2500*512 threads * 16B
#define TR_BLOCKS 3328    // weight transposes
#define CNT_BLOCKS 625    // count: ceil(160000/256)
#define EDGE_BLOCKS 2500  // N_EDGES / BM
#define NS_BLOCKS 157     // node_self tiles

typedef __attribute__((ext_vector_type(4))) float f32x4;
typedef __attribute__((ext_vector_type(8))) short bf16x8;
typedef __attribute__((ext_vector_type(4))) short bf16x4;

__device__ __forceinline__ short f2bf(float f) {
  unsigned u = __float_as_uint(f);
  u += 0x7fff + ((u >> 16) & 1);
  return (short)(u >> 16);
}
__device__ __forceinline__ float bf2f(short s) {
  return __uint_as_float(((unsigned)(unsigned short)s) << 16);
}
// tanh-form GELU in exp2 domain
__device__ __forceinline__ float gelu_f(float x) {
  float t = x * x;
  float zn = x * fmaf(t, -0.10293960f, -2.30220795f);
  return x * __builtin_amdgcn_rcpf(1.0f + __builtin_amdgcn_exp2f(zn));
}

#define GLDS(g, l) __builtin_amdgcn_global_load_lds( \
    (const __attribute__((address_space(1))) void*)(g), \
    (__attribute__((address_space(3))) void*)(l), 16, 0, 0)

// ---------------------------------------------------------------------------
// init: weight transposes f32->bf16 (blocks 0..3327) | in-degree count
// (3328..; icnt pre-zeroed by hipMemsetAsync).
// ---------------------------------------------------------------------------
__global__ __launch_bounds__(256) void init_kernel(
    int* __restrict__ icnt, const int* __restrict__ tgts,
    const float* __restrict__ w1, const float* __restrict__ sw,
    const float* __restrict__ aw,
    short* __restrict__ w1T, short* __restrict__ swT, short* __restrict__ awT)
{
  const int bx = blockIdx.x, tid = threadIdx.x;
  if (bx < TR_BLOCKS) {
    int id = bx * 256 + tid;
    const int NW1 = HID * K1, NSQ = HID * HID;
    if (id < NW1) {
      int n = id / K1, k = id - n * K1;
      w1T[id] = f2bf(w1[(size_t)k * HID + n]);
    } else if (id < NW1 + NSQ) {
      int i = id - NW1; int n = i >> 9, k = i & (HID - 1);
      swT[i] = f2bf(sw[(size_t)k * HID + n]);
    } else if (id < NW1 + 2 * NSQ) {
      int i = id - NW1 - NSQ; int n = i >> 9, k = i & (HID - 1);
      awT[i] = f2bf(aw[(size_t)k * HID + n]);
    }
  } else {
    int i = (bx - TR_BLOCKS) * 256 + tid;
    if (i < N_EDGES) atomicAdd(&icnt[tgts[i]], 1);
  }
}

// ---------------------------------------------------------------------------
// Fused dispatch:
//  blocks [0,157): Pb = bf16(ns @ w1_top + b1), PERMUTED col layout
//  blocks [157,166): [WT | bvec] = ([w2; b2] @ agg_w)
//  block  166: CSR scan (icnt -> cursor)
//  blocks [167,2667): hsum zeroing
// ---------------------------------------------------------------------------
__global__ __launch_bounds__(512, 2) void gemm_prep_kernel(
    const float* __restrict__ node_state, const float* __restrict__ b1,
    const short* __restrict__ w1T,
    short* __restrict__ Pb,
    const float* __restrict__ w2, const float* __restrict__ b2,
    const short* __restrict__ awT,
    short* __restrict__ WT, float* __restrict__ bvec,
    const int* __restrict__ icnt, int* __restrict__ cursor,
    float* __restrict__ hsum)
{
  const int tid = threadIdx.x;

  if (blockIdx.x > PRE_BLOCKS + 9) {
    int idx = (blockIdx.x - PRE_BLOCKS - 10) * 512 + tid;
    if (idx < N_NODES * HID / 4) {
      f32x4 z = {0.f, 0.f, 0.f, 0.f};
      *(f32x4*)(hsum + (size_t)idx * 4) = z;
    }
    return;
  }

  if (blockIdx.x == PRE_BLOCKS + 9) {
    // ---------------- scan path (512 threads, CH=20) ----------------
    __shared__ int sums[512];
    const int CH = 20;  // 512*20 = 10240 >= N_NODES
    int loc[CH];
    int s = 0;
#pragma unroll
    for (int i = 0; i < CH; ++i) {
      int idx = tid * CH + i;
      int v = (idx < N_NODES) ? icnt[idx] : 0;
      loc[i] = s; s += v;
    }
    sums[tid] = s;
    __syncthreads();
    for (int d = 1; d < 512; d <<= 1) {
      int v = (tid >= d) ? sums[tid - d] : 0;
      __syncthreads();
      sums[tid] += v;
      __syncthreads();
    }
    int base = (tid == 0) ? 0 : sums[tid - 1];
#pragma unroll
    for (int i = 0; i < CH; ++i) {
      int idx = tid * CH + i;
      if (idx < N_NODES) cursor[idx] = base + loc[i];
    }
    return;
  }

  __shared__ short As[2][BM * 32];
  __shared__ short Bs[2][HID * 32];

  const int lane = tid & 63, wv = tid >> 6;
  const int r16 = lane & 15, q4 = lane >> 4;
  const int arow = tid >> 2, auk = tid & 3;

  f32x4 acc[4][4] = {};
  f32x4 a0, a1;

  auto writeA = [&](int buf) {
    if (tid < 256) {
      bf16x8 v;
      v[0] = f2bf(a0[0]); v[1] = f2bf(a0[1]); v[2] = f2bf(a0[2]); v[3] = f2bf(a0[3]);
      v[4] = f2bf(a1[0]); v[5] = f2bf(a1[1]); v[6] = f2bf(a1[2]); v[7] = f2bf(a1[3]);
      int pos = arow * 4 + ((auk + (arow >> 1)) & 3);
      *(bf16x8*)(&As[buf][pos * 8]) = v;
    }
  };
  auto mma = [&](int buf) {
    bf16x8 af[4];
#pragma unroll
    for (int mi = 0; mi < 4; ++mi) {
      int row = mi * 16 + r16;
      int pos = row * 4 + ((q4 + (row >> 1)) & 3);
      af[mi] = *(const bf16x8*)(&As[buf][pos * 8]);
    }
#pragma unroll
    for (int ni = 0; ni < 4; ++ni) {
      int n = wv * 64 + ni * 16 + r16;
      int pos = n * 4 + ((q4 + (n >> 1)) & 3);
      bf16x8 bfr = *(const bf16x8*)(&Bs[buf][pos * 8]);
#pragma unroll
      for (int mi = 0; mi < 4; ++mi)
        acc[mi][ni] = __builtin_amdgcn_mfma_f32_16x16x32_bf16(af[mi], bfr, acc[mi][ni], 0, 0, 0);
    }
  };

  if (blockIdx.x < PRE_BLOCKS) {
    // ---------------- pre_msg path ----------------
    const int n0 = blockIdx.x * BM;
    float b1v[4];
#pragma unroll
    for (int ni = 0; ni < 4; ++ni) b1v[ni] = b1[wv * 64 + ni * 16 + r16];

    const int ga = min(n0 + arow, N_NODES - 1);
    auto loadA = [&](int k0) {
      if (tid < 256) {
        const float* p = node_state + (size_t)ga * HID + k0 + auk * 8;
        a0 = *(const f32x4*)p; a1 = *(const f32x4*)(p + 4);
      }
    };
    auto stageB = [&](int k0, int buf) {
#pragma unroll
      for (int i = 0; i < 4; ++i) {
        int q = i * 512 + tid;
        int n = q >> 2;
        int uk = ((q & 3) - (n >> 1)) & 3;
        GLDS(w1T + (size_t)n * K1 + k0 + uk * 8, &Bs[buf][(i * 512 + wv * 64) * 8]);
      }
    };

    stageB(0, 0); loadA(0); writeA(0);
    __syncthreads();
#pragma unroll 1
    for (int s = 0; s < 16; ++s) {
      int cur = s & 1, nxt = cur ^ 1;
      if (s < 15) { stageB((s + 1) * 32, nxt); loadA((s + 1) * 32); }
      mma(cur);
      if (s < 15) writeA(nxt);
      __syncthreads();
    }

    // permuted, packed 8B stores
#pragma unroll
    for (int mi = 0; mi < 4; ++mi)
#pragma unroll
      for (int j = 0; j < 4; ++j) {
        int g = n0 + mi * 16 + q4 * 4 + j;
        if (g < N_NODES) {
          bf16x4 pk;
#pragma unroll
          for (int ni = 0; ni < 4; ++ni) pk[ni] = f2bf(acc[mi][ni][j] + b1v[ni]);
          *(bf16x4*)(Pb + (size_t)g * HID + wv * 64 + r16 * 4) = pk;
        }
      }
  } else {
    // ---------------- wcombine path ----------------
    const int m0 = (blockIdx.x - PRE_BLOCKS) * BM;
    const int gm = min(m0 + arow, HID);   // HID => b2 row
    auto loadA = [&](int k0) {
      if (tid < 256) {
        const float* base = (gm < HID) ? w2 + (size_t)gm * HID : b2;
        const float* p = base + k0 + auk * 8;
        a0 = *(const f32x4*)p; a1 = *(const f32x4*)(p + 4);
      }
    };
    auto stageB = [&](int k0, int buf) {
#pragma unroll
      for (int i = 0; i < 4; ++i) {
        int q = i * 512 + tid;
        int n = q >> 2;
        int uk = ((q & 3) - (n >> 1)) & 3;
        GLDS(awT + (size_t)n * HID + k0 + uk * 8, &Bs[buf][(i * 512 + wv * 64) * 8]);
      }
    };

    stageB(0, 0); loadA(0); writeA(0);
    __syncthreads();
#pragma unroll 1
    for (int s = 0; s < 16; ++s) {
      int cur = s & 1, nxt = cur ^ 1;
      if (s < 15) { stageB((s + 1) * 32, nxt); loadA((s + 1) * 32); }
      mma(cur);
      if (s < 15) writeA(nxt);
      __syncthreads();
    }

#pragma unroll
    for (int mi = 0; mi < 4; ++mi)
#pragma unroll
      for (int j = 0; j < 4; ++j) {
        int m = m0 + mi * 16 + q4 * 4 + j;
        if (m < HID) {
#pragma unroll
          for (int ni = 0; ni < 4; ++ni)
            WT[(size_t)(wv * 64 + ni * 16 + r16) * HID + m] = f2bf(acc[mi][ni][j]);
        } else if (m == HID) {
#pragma unroll
          for (int ni = 0; ni < 4; ++ni)
            bvec[wv * 64 + ni * 16 + r16] = acc[mi][ni][j];
        }
      }
  }
}

// ---------------------------------------------------------------------------
// Edge dispatch (node_self FIRST so the heavy 16-stage blocks launch into an
// empty machine; 4-stage edge blocks backfill — removes the tail):
//  blocks [0,157): node_self — u1 = ns @ swT, PERMUTED f32x4 output
//  blocks [157,2657): edge tiles
// ---------------------------------------------------------------------------
__global__ __launch_bounds__(512, 2) void edge_msg_kernel(
    const float* __restrict__ edge_emb, const short* __restrict__ Pb,
    const int* __restrict__ srcs, const int* __restrict__ tgts,
    const int* __restrict__ sorted,
    const short* __restrict__ w1T,
    float* __restrict__ hsum,
    const float* __restrict__ node_state, const short* __restrict__ swT,
    float* __restrict__ u1)
{
  __shared__ short As[2][BM * 32];
  __shared__ short Bs[2][HID * 32];
  __shared__ int src_l[BM], eid_l[BM], tgt_l[BM];

  const int tid = threadIdx.x, lane = tid & 63, wv = tid >> 6;
  const int r16 = lane & 15, q4 = lane >> 4;
  const int arow = tid >> 2, auk = tid & 3;
  f32x4 a0, a1;

  auto writeA = [&](int buf) {
    if (tid < 256) {
      bf16x8 v;
      v[0] = f2bf(a0[0]); v[1] = f2bf(a0[1]); v[2] = f2bf(a0[2]); v[3] = f2bf(a0[3]);
      v[4] = f2bf(a1[0]); v[5] = f2bf(a1[1]); v[6] = f2bf(a1[2]); v[7] = f2bf(a1[3]);
      int pos = arow * 4 + ((auk + (arow >> 1)) & 3);
      *(bf16x8*)(&As[buf][pos * 8]) = v;
    }
  };

  if (blockIdx.x < NS_BLOCKS) {
    // ---------------- node_self path: u1 = ns @ swT ----------------
    const int n0 = blockIdx.x * BM;
    const int ga = min(n0 + arow, N_NODES - 1);

    f32x4 acc[4][4] = {};
    auto loadA = [&](int k0) {
      if (tid < 256) {
        const float* p = node_state + (size_t)ga * HID + k0 + auk * 8;
        a0 = *(const f32x4*)p; a1 = *(const f32x4*)(p + 4);
      }
    };
    auto stageB = [&](int k0, int buf) {
#pragma unroll
      for (int i = 0; i < 4; ++i) {
        int q = i * 512 + tid;
        int n = q >> 2;
        int uk = ((q & 3) - (n >> 1)) & 3;
        GLDS(swT + (size_t)n * HID + k0 + uk * 8, &Bs[buf][(i * 512 + wv * 64) * 8]);
      }
    };
    auto mma = [&](int buf) {
      bf16x8 af[4];
#pragma unroll
      for (int mi = 0; mi < 4; ++mi) {
        int row = mi * 16 + r16;
        int pos = row * 4 + ((q4 + (row >> 1)) & 3);
        af[mi] = *(const bf16x8*)(&As[buf][pos * 8]);
      }
#pragma unroll
      for (int ni = 0; ni < 4; ++ni) {
        int n = wv * 64 + ni * 16 + r16;
        int pos = n * 4 + ((q4 + (n >> 1)) & 3);
        bf16x8 bfr = *(const bf16x8*)(&Bs[buf][pos * 8]);
#pragma unroll
        for (int mi = 0; mi < 4; ++mi)
          acc[mi][ni] = __builtin_amdgcn_mfma_f32_16x16x32_bf16(af[mi], bfr, acc[mi][ni], 0, 0, 0);
      }
    };

    stageB(0, 0); loadA(0); writeA(0);
    __syncthreads();
#pragma unroll 1
    for (int s = 0; s < 16; ++s) {
      int cur = s & 1, nxt = cur ^ 1;
      if (s < 15) { stageB((s + 1) * 32, nxt); loadA((s + 1) * 32); }
      mma(cur);
      if (s < 15) writeA(nxt);
      __syncthreads();
    }

    // permuted f32x4 stores (mirror of Pb layout)
#pragma unroll
    for (int mi = 0; mi < 4; ++mi)
#pragma unroll
      for (int j = 0; j < 4; ++j) {
        int g = n0 + mi * 16 + q4 * 4 + j;
        if (g < N_NODES) {
          f32x4 uv;
#pragma unroll
          for (int ni = 0; ni < 4; ++ni) uv[ni] = acc[mi][ni][j];
          *(f32x4*)(u1 + (size_t)g * HID + wv * 64 + r16 * 4) = uv;
        }
      }
    return;
  }

  // ---------------- edge path ----------------
  const int e0 = (blockIdx.x - NS_BLOCKS) * BM;

  if (tid < BM) {
    int eid = sorted[e0 + tid];
    eid_l[tid] = eid;
    src_l[tid] = srcs[eid];
    tgt_l[tid] = tgts[eid];
  }
  __syncthreads();
  const int t_lane = tgt_l[lane];

  // acc pre-init: permuted Pb gather — one 8B load per row
  f32x4 acc[4][4];
#pragma unroll
  for (int mi = 0; mi < 4; ++mi)
#pragma unroll
    for (int j = 0; j < 4; ++j) {
      int row = mi * 16 + q4 * 4 + j;
      bf16x4 v = *(const bf16x4*)(Pb + (size_t)src_l[row] * HID + wv * 64 + r16 * 4);
#pragma unroll
      for (int ni = 0; ni < 4; ++ni)
        acc[mi][ni][j] = bf2f(v[ni]);
    }

  auto loadA = [&](int k0) {
    if (tid < 256) {
      const float* p = edge_emb + (size_t)eid_l[arow] * EDIM + k0 + auk * 8;
      a0 = *(const f32x4*)p; a1 = *(const f32x4*)(p + 4);
    }
  };
  auto stageB = [&](int k0, int buf) {
#pragma unroll
    for (int i = 0; i < 4; ++i) {
      int q = i * 512 + tid;
      int n = q >> 2;
      int uk = ((q & 3) - (n >> 1)) & 3;
      GLDS(w1T + (size_t)n * K1 + 512 + k0 + uk * 8, &Bs[buf][(i * 512 + wv * 64) * 8]);
    }
  };
  auto mma = [&](int buf) {
    bf16x8 af[4];
#pragma unroll
    for (int mi = 0; mi < 4; ++mi) {
      int row = mi * 16 + r16;
      int pos = row * 4 + ((q4 + (row >> 1)) & 3);
      af[mi] = *(const bf16x8*)(&As[buf][pos * 8]);
    }
#pragma unroll
    for (int ni = 0; ni < 4; ++ni) {
      int n = wv * 64 + ni * 16 + r16;
      int pos = n * 4 + ((q4 + (n >> 1)) & 3);
      bf16x8 bfr = *(const bf16x8*)(&Bs[buf][pos * 8]);
#pragma unroll
      for (int mi = 0; mi < 4; ++mi)
        acc[mi][ni] = __builtin_amdgcn_mfma_f32_16x16x32_bf16(af[mi], bfr, acc[mi][ni], 0, 0, 0);
    }
  };

  stageB(0, 0); loadA(0); writeA(0);
  __syncthreads();
#pragma unroll 1
  for (int s = 0; s < 4; ++s) {
    int cur = s & 1, nxt = cur ^ 1;
    if (s < 3) { stageB((s + 1) * 32, nxt); loadA((s + 1) * 32); }
    mma(cur);
    if (s < 3) writeA(nxt);
    __syncthreads();
  }

  // epilogue
#pragma unroll
  for (int mi = 0; mi < 4; ++mi)
#pragma unroll
    for (int ni = 0; ni < 4; ++ni)
#pragma unroll
      for (int j = 0; j < 4; ++j)
        acc[mi][ni][j] = gelu_f(acc[mi][ni][j]);

  int t_prev = __shfl_up(t_lane, 1, 64);
  bool bnd = (lane == 0) || (t_lane != t_prev);
  unsigned long long bmask = __ballot(bnd);

  int s = 0;
  while (s < BM) {
    int t = __shfl(t_lane, s, 64);
    unsigned long long above = (s < 63) ? (bmask >> (s + 1)) : 0ull;
    int e = (above == 0ull) ? BM : (s + 1 + (int)__builtin_ctzll(above));
    bool boundary = (s == 0) || (e == BM);

    float sum[4] = {0.f, 0.f, 0.f, 0.f};
#pragma unroll
    for (int mi = 0; mi < 4; ++mi) {
      if (e > mi * 16 && s < mi * 16 + 16) {  // wave-uniform skip
#pragma unroll
        for (int j = 0; j < 4; ++j) {
          int row = mi * 16 + q4 * 4 + j;
          bool in = (row >= s) && (row < e);
#pragma unroll
          for (int ni = 0; ni < 4; ++ni)
            sum[ni] += in ? acc[mi][ni][j] : 0.0f;
        }
      }
    }
#pragma unroll
    for (int ni = 0; ni < 4; ++ni) {
      sum[ni] += __shfl_xor(sum[ni], 16, 64);
      sum[ni] += __shfl_xor(sum[ni], 32, 64);
    }
    if (q4 == 0) {
      float* dst = hsum + (size_t)t * HID + wv * 64 + r16;
      if (boundary) {
#pragma unroll
        for (int ni = 0; ni < 4; ++ni) atomicAdd(dst + ni * 16, sum[ni]);
      } else {
#pragma unroll
        for (int ni = 0; ni < 4; ++ni) dst[ni * 16] = sum[ni];
      }
    }
    s = e;
  }
}

// ---------------------------------------------------------------------------
// node_final: acc = (hsum*invc) @ WT (16 K-steps);
// u = acc + u1 + self_b+agg_b + flag*bvec; out = LN(ns + gelu(u))
// ---------------------------------------------------------------------------
__global__ __launch_bounds__(512, 2) void node_final_kernel(
    const float* __restrict__ node_state, const float* __restrict__ hsum,
    const float* __restrict__ u1,
    const int* __restrict__ icnt,
    const short* __restrict__ WT,
    const float* __restrict__ self_b, const float* __restrict__ agg_b,
    const float* __restrict__ bvec,
    const float* __restrict__ gamma, const float* __restrict__ beta,
    float* __restrict__ out)
{
  __shared__ short As[2][BM * 32];
  __shared__ short Bs[2][HID * 32];
  __shared__ float cfl[BM], invc_l[BM];
  __shared__ float wsum[8][BM], wsq[8][BM];
  __shared__ float stats[BM][2];

  const int tid = threadIdx.x, lane = tid & 63, wv = tid >> 6;
  const int r16 = lane & 15, q4 = lane >> 4;
  const int n0 = blockIdx.x * BM;

  if (tid < BM) {
    int g = n0 + tid;
    int c = (g < N_NODES) ? icnt[g] : 0;
    cfl[tid] = (c > 0) ? 1.0f : 0.0f;
    invc_l[tid] = 1.0f / (float)max(c, 1);
  }

  float bb[4], bv[4], gam[4], bet[4];
#pragma unroll
  for (int ni = 0; ni < 4; ++ni) {
    int c = wv * 64 + ni * 16 + r16;
    bb[ni] = self_b[c] + agg_b[c];
    bv[ni] = bvec[c];
    gam[ni] = gamma[c]; bet[ni] = beta[c];
  }
  __syncthreads();

  const int arow = tid >> 2, auk = tid & 3;
  const int ga = min(n0 + arow, N_NODES - 1);
  f32x4 a0, a1;

  auto loadA = [&](int k0) {
    if (tid < 256) {
      const float* p = hsum + (size_t)ga * HID + k0 + auk * 8;
      a0 = *(const f32x4*)p; a1 = *(const f32x4*)(p + 4);
      float s = invc_l[arow]; a0 *= s; a1 *= s;
    }
  };
  auto writeA = [&](int buf) {
    if (tid < 256) {
      bf16x8 v;
      v[0] = f2bf(a0[0]); v[1] = f2bf(a0[1]); v[2] = f2bf(a0[2]); v[3] = f2bf(a0[3]);
      v[4] = f2bf(a1[0]); v[5] = f2bf(a1[1]); v[6] = f2bf(a1[2]); v[7] = f2bf(a1[3]);
      int pos = arow * 4 + ((auk + (arow >> 1)) & 3);
      *(bf16x8*)(&As[buf][pos * 8]) = v;
    }
  };
  auto stageB = [&](int k0, int buf) {
#pragma unroll
    for (int i = 0; i < 4; ++i) {
      int q = i * 512 + tid;
      int n = q >> 2;
      int uk = ((q & 3) - (n >> 1)) & 3;
      GLDS(WT + (size_t)n * HID + k0 + uk * 8, &Bs[buf][(i * 512 + wv * 64) * 8]);
    }
  };

  f32x4 acc[4][4] = {};

  auto mma = [&](int buf) {
    bf16x8 af[4];
#pragma unroll
    for (int mi = 0; mi < 4; ++mi) {
      int row = mi * 16 + r16;
      int pos = row * 4 + ((q4 + (row >> 1)) & 3);
      af[mi] = *(const bf16x8*)(&As[buf][pos * 8]);
    }
#pragma unroll
    for (int ni = 0; ni < 4; ++ni) {
      int n = wv * 64 + ni * 16 + r16;
      int pos = n * 4 + ((q4 + (n >> 1)) & 3);
      bf16x8 bfr = *(const bf16x8*)(&Bs[buf][pos * 8]);
#pragma unroll
      for (int mi = 0; mi < 4; ++mi)
        acc[mi][ni] = __builtin_amdgcn_mfma_f32_16x16x32_bf16(af[mi], bfr, acc[mi][ni], 0, 0, 0);
    }
  };

  stageB(0, 0);
  loadA(0); writeA(0);
  __syncthreads();
#pragma unroll 1
  for (int s = 0; s < 16; ++s) {
    int cur = s & 1, nxt = cur ^ 1;
    if (s < 15) { stageB((s + 1) * 32, nxt); loadA((s + 1) * 32); }
    mma(cur);
    if (s < 15) writeA(nxt);
    __syncthreads();
  }

  // epilogue: + u1 (permuted f32x4) + biases, gelu, residual, LN
  float ps[4][4], ps2[4][4];
#pragma unroll
  for (int mi = 0; mi < 4; ++mi)
#pragma unroll
    for (int j = 0; j < 4; ++j) {
      int row = mi * 16 + q4 * 4 + j;
      int g = min(n0 + row, N_NODES - 1);
      float fl = cfl[row];
      f32x4 uv = *(const f32x4*)(u1 + (size_t)g * HID + wv * 64 + r16 * 4);
      float s1 = 0.f, s2 = 0.f;
#pragma unroll
      for (int ni = 0; ni < 4; ++ni) {
        float u = acc[mi][ni][j] + uv[ni] + bb[ni] + fl * bv[ni];
        float ns = node_state[(size_t)g * HID + wv * 64 + ni * 16 + r16];
        float x = ns + gelu_f(u);
        acc[mi][ni][j] = x;
        s1 += x; s2 += x * x;
      }
      ps[mi][j] = s1; ps2[mi][j] = s2;
    }
#pragma unroll
  for (int mi = 0; mi < 4; ++mi)
#pragma unroll
    for (int j = 0; j < 4; ++j) {
#pragma unroll
      for (int m = 1; m < 16; m <<= 1) {
        ps[mi][j] += __shfl_xor(ps[mi][j], m, 64);
        ps2[mi][j] += __shfl_xor(ps2[mi][j], m, 64);
      }
    }
  if (r16 == 0) {
#pragma unroll
    for (int mi = 0; mi < 4; ++mi)
#pragma unroll
      for (int j = 0; j < 4; ++j) {
        int row = mi * 16 + q4 * 4 + j;
        wsum[wv][row] = ps[mi][j]; wsq[wv][row] = ps2[mi][j];
      }
  }
  __syncthreads();
  if (tid < BM) {
    float s1 = 0.f, s2 = 0.f;
#pragma unroll
    for (int k = 0; k < 8; ++k) { s1 += wsum[k][tid]; s2 += wsq[k][tid]; }
    float mu = s1 * (1.0f / HID);
    float var = s2 * (1.0f / HID) - mu * mu;
    stats[tid][0] = mu; stats[tid][1] = rsqrtf(var + LN_EPS);
  }
  __syncthreads();
#pragma unroll
  for (int mi = 0; mi < 4; ++mi)
#pragma unroll
    for (int j = 0; j < 4; ++j) {
      int row = mi * 16 + q4 * 4 + j;
      int g = n0 + row;
      if (g < N_NODES) {
        float mu = stats[row][0], rs = stats[row][1];
#pragma unroll
        for (int ni = 0; ni < 4; ++ni)
          out[(size_t)g * HID + wv * 64 + ni * 16 + r16] =
              (acc[mi][ni][j] - mu) * rs * gam[ni] + bet[ni];
      }
    }
}

// ---------------------------------------------------------------------------
// fill: scatter edge ids into target-sorted order
// ---------------------------------------------------------------------------
__global__ void fill_kernel(const int* __restrict__ tgt, int* __restrict__ cursor,
                            int* __restrict__ sorted)
{
  int i = blockIdx.x * 256 + threadIdx.x;
  if (i < N_EDGES) {
    int tg = tgt[i];
    int p = atomicAdd(&cursor[tg], 1);
    sorted[p] = i;
  }
}

// ---------------------------------------------------------------------------
extern "C" void kernel_launch(void* const* d_in, const int* in_sizes, int n_in,
                              void* d_out, int out_size, void* d_ws, size_t ws_size,
                              hipStream_t stream)
{
  const float* node_state = (const float*)d_in[0];
  const int*   eidx       = (const int*)d_in[1];
  const float* edge_emb   = (const float*)d_in[2];
  const float* msg_w1     = (const float*)d_in[3];
  const float* msg_b1     = (const float*)d_in[4];
  const float* msg_w2     = (const float*)d_in[5];
  const float* msg_b2     = (const float*)d_in[6];
  const float* self_w     = (const float*)d_in[7];
  const float* self_b     = (const float*)d_in[8];
  const float* agg_w      = (const float*)d_in[9];
  const float* agg_b      = (const float*)d_in[10];
  const float* ln_gamma   = (const float*)d_in[11];
  const float* ln_beta    = (const float*)d_in[12];

  const int* srcs = eidx;
  const int* tgts = eidx + N_EDGES;
  float* out = (float*)d_out;
  char* ws = (char*)d_ws;

  float* hsum    = (float*)ws;                      // 20,480,000
  float* u1      = (float*)(ws + 20480000);         // 20,480,000
  short* Pb      = (short*)(ws + 40960000);         // 10,240,000
  int* icnt      = (int*)(ws + 51200000);           //     40,000
  int* cursor    = (int*)(ws + 51240192);           //     40,000
  int* sorted    = (int*)(ws + 51280384);           //    640,000
  short* w1T     = (short*)(ws + 51920384);         //    655,360
  short* swT     = (short*)(ws + 52575744);         //    524,288
  short* WT      = (short*)(ws + 53100032);         //    524,288
  short* awT     = (short*)(ws + 53624320);         //    524,288
  float* bvec    = (float*)(ws + 54148608);         //      2,048

  // 0) zero icnt (init's count blocks accumulate into it)
  hipMemsetAsync(icnt, 0, 40000, stream);

  // 1) init: weight transposes (3328) | in-degree count (625)
  init_kernel<<<TR_BLOCKS + CNT_BLOCKS, 256, 0, stream>>>(
      icnt, tgts, msg_w1, self_w, agg_w, w1T, swT, awT);

  // 2) pre_msg (157) || wcombine (9) || scan (1) || hsum zero (2500)
  gemm_prep_kernel<<<PRE_BLOCKS + 10 + ZB_BLOCKS, 512, 0, stream>>>(
      node_state, msg_b1, w1T, Pb, msg_w2, msg_b2, awT, WT, bvec,
      icnt, cursor, hsum);

  // 3) fill (sorted ids)
  fill_kernel<<<(N_EDGES + 255) / 256, 256, 0, stream>>>(tgts, cursor, sorted);

  // 4) node_self u1 = ns @ swT (157, first) || edge tiles (2500)
  edge_msg_kernel<<<NS_BLOCKS + EDGE_BLOCKS, 512, 0, stream>>>(
      edge_emb, Pb, srcs, tgts, sorted, w1T, hsum, node_state, swT, u1);

  // 5) node_final: K=512 (hmean @ WT) + u1 + epilogue/LN
  node_final_kernel<<<(N_NODES + BM - 1) / BM, 512, 0, stream>>>(
      node_state, hsum, u1, icnt, WT, self_b, agg_b, bvec, ln_gamma, ln_beta, out);
}